// Round 1
// baseline (766.125 us; speedup 1.0000x reference)
//
#include <hip/hip_runtime.h>

// ---------- types / helpers ----------
typedef __attribute__((ext_vector_type(8))) short s16x8;
typedef __attribute__((ext_vector_type(4))) short s16x4;
typedef __attribute__((ext_vector_type(4))) float f32x4;

#define MFMA16(a, b, c) __builtin_amdgcn_mfma_f32_16x16x32_bf16(a, b, c, 0, 0, 0)

__device__ __forceinline__ unsigned short f2b(float f) {
  unsigned u = __float_as_uint(f);
  u = u + 0x7fffu + ((u >> 16) & 1u);          // RNE
  return (unsigned short)(u >> 16);
}
__device__ __forceinline__ float b2f(unsigned short u) {
  return __uint_as_float(((unsigned)u) << 16);
}

// problem constants
// B=16 S=512 H=16 DH=64 D=1024, BH=256

// ---------- K0a: X fp32 -> bf16, + per-head gate ----------
__global__ __launch_bounds__(256) void k0a_convx_gate(
    const float* __restrict__ X, const float* __restrict__ gw,
    const float* __restrict__ gb, unsigned short* __restrict__ Xb,
    float* __restrict__ gate) {
  int row = blockIdx.x;              // b*512 + s, 0..8191
  int t = threadIdx.x;               // 256
  const float* xr = X + (size_t)row * 1024;
  float4 x = *(const float4*)(xr + t * 4);
  s16x4 o;
  o.x = (short)f2b(x.x); o.y = (short)f2b(x.y);
  o.z = (short)f2b(x.z); o.w = (short)f2b(x.w);
  *(s16x4*)(&Xb[(size_t)row * 1024 + t * 4]) = o;
  // gate: head h = t>>4, 16 threads per head, 4 elems each
  int h = t >> 4;
  int e0 = (t & 15) * 4;
  const float* g4 = gw + h * 64 + e0;
  float part = x.x * g4[0] + x.y * g4[1] + x.z * g4[2] + x.w * g4[3];
  part += __shfl_xor(part, 1);
  part += __shfl_xor(part, 2);
  part += __shfl_xor(part, 4);
  part += __shfl_xor(part, 8);
  if ((t & 15) == 0) {
    int b = row >> 9, s = row & 511;
    float z = part + gb[h];
    gate[((size_t)(b * 16 + h)) * 512 + s] = 1.0f / (1.0f + __expf(-z));
  }
}

// ---------- K0b: W [k][n] fp32 -> Wt [n][k] bf16 (x3) ----------
__global__ __launch_bounds__(256) void k0b_wtrans(
    const float* __restrict__ Wq, const float* __restrict__ Wk,
    const float* __restrict__ Wv, unsigned short* __restrict__ Wt) {
  __shared__ float tile[64][68];
  int z = blockIdx.z;
  const float* W = (z == 0) ? Wq : (z == 1) ? Wk : Wv;
  unsigned short* O = Wt + (size_t)z * 1024 * 1024;
  int k0 = blockIdx.x * 64, n0 = blockIdx.y * 64;
  int t = threadIdx.x;
  int kl = t >> 4, nl = (t & 15) * 4;
#pragma unroll
  for (int p = 0; p < 4; ++p) {
    float4 v = *(const float4*)(W + (size_t)(k0 + p * 16 + kl) * 1024 + n0 + nl);
    tile[p * 16 + kl][nl + 0] = v.x;
    tile[p * 16 + kl][nl + 1] = v.y;
    tile[p * 16 + kl][nl + 2] = v.z;
    tile[p * 16 + kl][nl + 3] = v.w;
  }
  __syncthreads();
  for (int idx = t; idx < 4096; idx += 256) {
    int nl2 = idx >> 6, kl2 = idx & 63;
    O[(size_t)(n0 + nl2) * 1024 + k0 + kl2] = f2b(tile[kl2][nl2]);
  }
}

// ---------- K0c: dist_emb -> bf16 padded to 1024 rows ----------
__global__ __launch_bounds__(256) void k0c_conve(const float* __restrict__ E,
                                                 unsigned short* __restrict__ Eb) {
  int idx = blockIdx.x * 256 + threadIdx.x;   // < 65536
  int row = idx >> 6;
  float v = (row < 1023) ? E[idx] : 0.0f;
  Eb[idx] = f2b(v);
}

// ---------- K1: QKV GEMM  Xb[8192,1024] @ W -> Q/K bf16 [bh][s][dh], V -> Vt [bh][dh][s] ----------
__global__ __launch_bounds__(256) void k1_qkv(
    const unsigned short* __restrict__ Xb, const unsigned short* __restrict__ Wt,
    const float* __restrict__ bq, const float* __restrict__ bk,
    const float* __restrict__ bv, unsigned short* __restrict__ Qb,
    unsigned short* __restrict__ Kb, unsigned short* __restrict__ Vt) {
  __shared__ short As[128 * 72];
  __shared__ short Ws[128 * 72];
  int t = threadIdx.x;
  int wv = t >> 6, lane = t & 63, quad = lane >> 4, l15 = lane & 15;
  int wm = wv >> 1, wn = wv & 1;
  int m0 = blockIdx.x * 128, n0 = blockIdx.y * 128, z = blockIdx.z;
  const unsigned short* W = Wt + (size_t)z * 1024 * 1024;
  f32x4 acc[4][4];
#pragma unroll
  for (int i = 0; i < 4; ++i)
#pragma unroll
    for (int j = 0; j < 4; ++j) acc[i][j] = (f32x4){0.f, 0.f, 0.f, 0.f};

  for (int kt = 0; kt < 16; ++kt) {
    int k0 = kt * 64;
    __syncthreads();
#pragma unroll
    for (int p = 0; p < 4; ++p) {
      int g = p * 256 + t;
      int row = g >> 3, cg = g & 7;
      int4 va = *(const int4*)(Xb + (size_t)(m0 + row) * 1024 + k0 + cg * 8);
      *(int4*)(&As[row * 72 + cg * 8]) = va;
      int4 vb = *(const int4*)(W + (size_t)(n0 + row) * 1024 + k0 + cg * 8);
      *(int4*)(&Ws[row * 72 + cg * 8]) = vb;
    }
    __syncthreads();
#pragma unroll
    for (int ks = 0; ks < 2; ++ks) {
      s16x8 a[4], bb[4];
#pragma unroll
      for (int i = 0; i < 4; ++i)
        a[i] = *(const s16x8*)(&As[(wm * 64 + i * 16 + l15) * 72 + ks * 32 + quad * 8]);
#pragma unroll
      for (int j = 0; j < 4; ++j)
        bb[j] = *(const s16x8*)(&Ws[(wn * 64 + j * 16 + l15) * 72 + ks * 32 + quad * 8]);
#pragma unroll
      for (int i = 0; i < 4; ++i)
#pragma unroll
        for (int j = 0; j < 4; ++j)
          acc[i][j] = MFMA16(a[i], bb[j], acc[i][j]);
    }
  }
  const float* bias = (z == 0) ? bq : (z == 1) ? bk : bv;
#pragma unroll
  for (int i = 0; i < 4; ++i) {
    int mbase = m0 + wm * 64 + i * 16 + quad * 4;
#pragma unroll
    for (int j = 0; j < 4; ++j) {
      int n = n0 + wn * 64 + j * 16 + l15;
      float bvv = bias[n];
      int h = n >> 6, dh = n & 63;
#pragma unroll
      for (int r = 0; r < 4; ++r) {
        int m = mbase + r;
        int b = m >> 9, s = m & 511;
        unsigned short u = f2b(acc[i][j][r] + bvv);
        if (z == 2)
          Vt[(size_t)((b * 16 + h) * 64 + dh) * 512 + s] = u;
        else if (z == 0)
          Qb[(size_t)((b * 16 + h) * 512 + s) * 64 + dh] = u;
        else
          Kb[(size_t)((b * 16 + h) * 512 + s) * 64 + dh] = u;
      }
    }
  }
}

// ---------- K2: fused attention per (bh, q-tile of 64) ----------
// scores (regs) = QK^T + diag-gather(Q@E^T) + diag-gather(K@E^T); softmax+clip; P@V; *gate
__global__ __launch_bounds__(256, 2) void k2_attn(
    const unsigned short* __restrict__ Qb, const unsigned short* __restrict__ Kb,
    const unsigned short* __restrict__ Vt, const unsigned short* __restrict__ Eb,
    const float* __restrict__ gate, const float* __restrict__ mask,
    float* __restrict__ out) {
  __shared__ char smem[62464];
  short* Ks = (short*)(smem);             // [64][72]   scores phase
  short* Es = (short*)(smem + 9216);      // [128][72]
  short* Ss1 = (short*)(smem + 27648);    // [128 t][68 r]  col-major, bf16
  short* Ss2 = (short*)(smem + 45056);    // [128 t][68 r]
  short* Vs = (short*)(smem);             // [64][136]  PV phase
  short* Ps = (short*)(smem + 17408);     // [64][264]  PV phase

  int t = threadIdx.x;
  int wv = t >> 6, lane = t & 63, quad = lane >> 4, l15 = lane & 15;
  int bid = blockIdx.x;
  int bh = bid >> 3, qt = bid & 7;
  int b = bh >> 4, hh = bh & 15;
  int l0 = qt * 64;

  // Q A-frags for this wave's 16 q rows (constant all phases)
  s16x8 aq0, aq1;
  {
    const unsigned short* qp = Qb + ((size_t)bh * 512 + l0 + wv * 16 + l15) * 64 + quad * 8;
    aq0 = *(const s16x8*)(qp);
    aq1 = *(const s16x8*)(qp + 32);
  }
  f32x4 acc[32];
#pragma unroll
  for (int f = 0; f < 32; ++f) acc[f] = (f32x4){0.f, 0.f, 0.f, 0.f};

  for (int kt = 0; kt < 8; ++kt) {
    int r0 = kt * 64;
    __syncthreads();
    // stage K tile (64x64): 512 granules
#pragma unroll
    for (int p = 0; p < 2; ++p) {
      int g = p * 256 + t;
      int row = g >> 3, cg = g & 7;
      int4 v = *(const int4*)(Kb + ((size_t)bh * 512 + r0 + row) * 64 + cg * 8);
      *(int4*)(&Ks[row * 72 + cg * 8]) = v;
    }
    // stage E window (128x64): rows estart..estart+127
    int estart = (qt - kt) * 64 + 448;
#pragma unroll
    for (int p = 0; p < 4; ++p) {
      int g = p * 256 + t;
      int row = g >> 3, cg = g & 7;
      int4 v = *(const int4*)(Eb + (size_t)(estart + row) * 64 + cg * 8);
      *(int4*)(&Es[row * 72 + cg * 8]) = v;
    }
    __syncthreads();
    // A-frags for S2 (this wave's 16 k rows)
    s16x8 ak0 = *(const s16x8*)(&Ks[(wv * 16 + l15) * 72 + quad * 8]);
    s16x8 ak1 = *(const s16x8*)(&Ks[(wv * 16 + l15) * 72 + 32 + quad * 8]);
    // S1 = Q@E^T, S2 = K@E^T  -> LDS col-major bf16
#pragma unroll
    for (int nf = 0; nf < 8; ++nf) {
      s16x8 b0 = *(const s16x8*)(&Es[(nf * 16 + l15) * 72 + quad * 8]);
      s16x8 b1 = *(const s16x8*)(&Es[(nf * 16 + l15) * 72 + 32 + quad * 8]);
      f32x4 s1 = (f32x4){0.f, 0.f, 0.f, 0.f};
      s1 = MFMA16(aq0, b0, s1);
      s1 = MFMA16(aq1, b1, s1);
      s16x4 w1;
      w1.x = (short)f2b(s1[0]); w1.y = (short)f2b(s1[1]);
      w1.z = (short)f2b(s1[2]); w1.w = (short)f2b(s1[3]);
      *(s16x4*)(&Ss1[(nf * 16 + l15) * 68 + wv * 16 + quad * 4]) = w1;
      f32x4 s2 = (f32x4){0.f, 0.f, 0.f, 0.f};
      s2 = MFMA16(ak0, b0, s2);
      s2 = MFMA16(ak1, b1, s2);
      s16x4 w2;
      w2.x = (short)f2b(s2[0]); w2.y = (short)f2b(s2[1]);
      w2.z = (short)f2b(s2[2]); w2.w = (short)f2b(s2[3]);
      *(s16x4*)(&Ss2[(nf * 16 + l15) * 68 + wv * 16 + quad * 4]) = w2;
    }
    // QK^T for this k-tile
#pragma unroll
    for (int nf = 0; nf < 4; ++nf) {
      s16x8 b0 = *(const s16x8*)(&Ks[(nf * 16 + l15) * 72 + quad * 8]);
      s16x8 b1 = *(const s16x8*)(&Ks[(nf * 16 + l15) * 72 + 32 + quad * 8]);
      f32x4 d = acc[kt * 4 + nf];
      d = MFMA16(aq0, b0, d);
      d = MFMA16(aq1, b1, d);
      acc[kt * 4 + nf] = d;
    }
    __syncthreads();
    // diagonal gather of positional terms into score accs
#pragma unroll
    for (int nf = 0; nf < 4; ++nf) {
      int dr = nf * 16 + l15;
#pragma unroll
      for (int r = 0; r < 4; ++r) {
        int dl = wv * 16 + quad * 4 + r;
        int tt = dl - dr + 63;   // 0..126
        float p1 = b2f((unsigned short)Ss1[tt * 68 + dl]);
        float p2 = b2f((unsigned short)Ss2[tt * 68 + dr]);
        acc[kt * 4 + nf][r] += p1 + p2;
      }
    }
  }

  // ---- softmax + clip (rows = wv*16 + quad*4 + r; cols f*16+l15) ----
#pragma unroll
  for (int f = 0; f < 32; ++f) {
    float mk = mask[b * 512 + f * 16 + l15];
#pragma unroll
    for (int r = 0; r < 4; ++r) acc[f][r] = acc[f][r] * 0.125f + mk;
  }
  float rinv[4];
#pragma unroll
  for (int r = 0; r < 4; ++r) {
    float m = -1e30f;
#pragma unroll
    for (int f = 0; f < 32; ++f) m = fmaxf(m, acc[f][r]);
    m = fmaxf(m, __shfl_xor(m, 1));
    m = fmaxf(m, __shfl_xor(m, 2));
    m = fmaxf(m, __shfl_xor(m, 4));
    m = fmaxf(m, __shfl_xor(m, 8));
    float l = 0.f;
#pragma unroll
    for (int f = 0; f < 32; ++f) {
      float e = __expf(acc[f][r] - m);
      acc[f][r] = e;
      l += e;
    }
    l += __shfl_xor(l, 1);
    l += __shfl_xor(l, 2);
    l += __shfl_xor(l, 4);
    l += __shfl_xor(l, 8);
    rinv[r] = 1.0f / l;
  }
#pragma unroll
  for (int f = 0; f < 32; ++f)
#pragma unroll
    for (int r = 0; r < 4; ++r) {
      float p = acc[f][r] * rinv[r] * 1.0234375f - 0.0234375f;
      acc[f][r] = fminf(fmaxf(p, 0.0f), 1.0f);
    }

  // ---- PV: ctx[64 q][64 dh], via Ps halves (256 keys) and Vs chunks (128 keys) ----
  f32x4 acc2[4];
#pragma unroll
  for (int nf = 0; nf < 4; ++nf) acc2[nf] = (f32x4){0.f, 0.f, 0.f, 0.f};

  for (int h = 0; h < 2; ++h) {
    __syncthreads();  // prior LDS readers done (Ss gathers / previous Vs chunk)
#pragma unroll
    for (int ff = 0; ff < 16; ++ff) {
      int f = h * 16 + ff;
      int row = wv * 16 + quad * 4;
#pragma unroll
      for (int r = 0; r < 4; ++r)
        Ps[(row + r) * 264 + ff * 16 + l15] = (short)f2b(acc[f][r]);
    }
    for (int c = 0; c < 2; ++c) {
      __syncthreads();  // Ps visible / previous Vs chunk reads done
      int kb = h * 256 + c * 128;
#pragma unroll
      for (int p = 0; p < 4; ++p) {
        int g = p * 256 + t;
        int row = g >> 4, cg = g & 15;
        int4 v = *(const int4*)(Vt + ((size_t)bh * 64 + row) * 512 + kb + cg * 8);
        *(int4*)(&Vs[row * 136 + cg * 8]) = v;
      }
      __syncthreads();
#pragma unroll
      for (int ks = 0; ks < 4; ++ks) {
        s16x8 a = *(const s16x8*)(&Ps[(wv * 16 + l15) * 264 + c * 128 + ks * 32 + quad * 8]);
#pragma unroll
        for (int nf = 0; nf < 4; ++nf) {
          s16x8 bb = *(const s16x8*)(&Vs[(nf * 16 + l15) * 136 + ks * 32 + quad * 8]);
          acc2[nf] = MFMA16(a, bb, acc2[nf]);
        }
      }
    }
  }

  // ---- epilogue: * gate, write out [b][s][h*64+dh] fp32 ----
#pragma unroll
  for (int r = 0; r < 4; ++r) {
    int s = l0 + wv * 16 + quad * 4 + r;
    float g = gate[(size_t)bh * 512 + s];
#pragma unroll
    for (int nf = 0; nf < 4; ++nf)
      out[((size_t)(b * 512 + s)) * 1024 + hh * 64 + nf * 16 + l15] = acc2[nf][r] * g;
  }
}

// ---------- launch ----------
extern "C" void kernel_launch(void* const* d_in, const int* in_sizes, int n_in,
                              void* d_out, int out_size, void* d_ws, size_t ws_size,
                              hipStream_t stream) {
  const float* X = (const float*)d_in[0];
  const float* mask = (const float*)d_in[1];
  const float* Wq = (const float*)d_in[2];
  const float* bq = (const float*)d_in[3];
  const float* Wk = (const float*)d_in[4];
  const float* bk = (const float*)d_in[5];
  const float* Wv = (const float*)d_in[6];
  const float* bv = (const float*)d_in[7];
  const float* dist = (const float*)d_in[8];
  const float* gw = (const float*)d_in[9];
  const float* gb = (const float*)d_in[10];
  float* out = (float*)d_out;

  char* ws = (char*)d_ws;
  constexpr size_t OFF_XB = 0;                       // 8192*1024*2 = 16 MB
  constexpr size_t OFF_WT = 16777216;                // 3*1024*1024*2 = 6 MB
  constexpr size_t OFF_QB = OFF_WT + 6291456;        // 16 MB
  constexpr size_t OFF_KB = OFF_QB + 16777216;       // 16 MB
  constexpr size_t OFF_VT = OFF_KB + 16777216;       // 16 MB
  constexpr size_t OFF_EB = OFF_VT + 16777216;       // 1024*64*2
  constexpr size_t OFF_GA = OFF_EB + 131072;         // 256*512*4

  unsigned short* Xb = (unsigned short*)(ws + OFF_XB);
  unsigned short* Wt = (unsigned short*)(ws + OFF_WT);
  unsigned short* Qb = (unsigned short*)(ws + OFF_QB);
  unsigned short* Kb = (unsigned short*)(ws + OFF_KB);
  unsigned short* Vt = (unsigned short*)(ws + OFF_VT);
  unsigned short* Eb = (unsigned short*)(ws + OFF_EB);
  float* gate = (float*)(ws + OFF_GA);

  hipLaunchKernelGGL(k0a_convx_gate, dim3(8192), dim3(256), 0, stream, X, gw, gb, Xb, gate);
  hipLaunchKernelGGL(k0b_wtrans, dim3(16, 16, 3), dim3(256), 0, stream, Wq, Wk, Wv, Wt);
  hipLaunchKernelGGL(k0c_conve, dim3(256), dim3(256), 0, stream, dist, Eb);
  hipLaunchKernelGGL(k1_qkv, dim3(64, 8, 3), dim3(256), 0, stream,
                     Xb, Wt, bq, bk, bv, Qb, Kb, Vt);
  hipLaunchKernelGGL(k2_attn, dim3(2048), dim3(256), 0, stream,
                     Qb, Kb, Vt, Eb, gate, mask, out);
}

// Round 3
// 547.720 us; speedup vs baseline: 1.3988x; 1.3988x over previous
//
#include <hip/hip_runtime.h>

// ---------- types / helpers ----------
typedef __attribute__((ext_vector_type(8))) short s16x8;
typedef __attribute__((ext_vector_type(4))) short s16x4;
typedef __attribute__((ext_vector_type(4))) float f32x4;

__device__ __forceinline__ f32x4 mfma16(s16x8 a, s16x8 b, f32x4 c) {
  return __builtin_amdgcn_mfma_f32_16x16x32_bf16(a, b, c, 0, 0, 0);
}
__device__ __forceinline__ f32x4 zero4() {
  f32x4 z = {0.f, 0.f, 0.f, 0.f};
  return z;
}

__device__ __forceinline__ unsigned short f2b(float f) {
  unsigned u = __float_as_uint(f);
  u = u + 0x7fffu + ((u >> 16) & 1u);          // RNE
  return (unsigned short)(u >> 16);
}
__device__ __forceinline__ float b2f(unsigned short u) {
  return __uint_as_float(((unsigned)u) << 16);
}

// problem constants
// B=16 S=512 H=16 DH=64 D=1024, BH=256

// ---------- K0a: X fp32 -> bf16, + per-head gate ----------
__global__ __launch_bounds__(256) void k0a_convx_gate(
    const float* __restrict__ X, const float* __restrict__ gw,
    const float* __restrict__ gb, unsigned short* __restrict__ Xb,
    float* __restrict__ gate) {
  int row = blockIdx.x;              // b*512 + s, 0..8191
  int t = threadIdx.x;               // 256
  const float* xr = X + (size_t)row * 1024;
  float4 x = *(const float4*)(xr + t * 4);
  s16x4 o;
  o.x = (short)f2b(x.x); o.y = (short)f2b(x.y);
  o.z = (short)f2b(x.z); o.w = (short)f2b(x.w);
  *(s16x4*)(&Xb[(size_t)row * 1024 + t * 4]) = o;
  // gate: head h = t>>4, 16 threads per head, 4 elems each
  int h = t >> 4;
  int e0 = (t & 15) * 4;
  const float* g4 = gw + h * 64 + e0;
  float part = x.x * g4[0] + x.y * g4[1] + x.z * g4[2] + x.w * g4[3];
  part += __shfl_xor(part, 1);
  part += __shfl_xor(part, 2);
  part += __shfl_xor(part, 4);
  part += __shfl_xor(part, 8);
  if ((t & 15) == 0) {
    int b = row >> 9, s = row & 511;
    float z = part + gb[h];
    gate[((size_t)(b * 16 + h)) * 512 + s] = 1.0f / (1.0f + __expf(-z));
  }
}

// ---------- K0b: W [k][n] fp32 -> Wt [n][k] bf16 (x3) ----------
__global__ __launch_bounds__(256) void k0b_wtrans(
    const float* __restrict__ Wq, const float* __restrict__ Wk,
    const float* __restrict__ Wv, unsigned short* __restrict__ Wt) {
  __shared__ float tile[64][68];
  int z = blockIdx.z;
  const float* W = (z == 0) ? Wq : (z == 1) ? Wk : Wv;
  unsigned short* O = Wt + (size_t)z * 1024 * 1024;
  int k0 = blockIdx.x * 64, n0 = blockIdx.y * 64;
  int t = threadIdx.x;
  int kl = t >> 4, nl = (t & 15) * 4;
#pragma unroll
  for (int p = 0; p < 4; ++p) {
    float4 v = *(const float4*)(W + (size_t)(k0 + p * 16 + kl) * 1024 + n0 + nl);
    tile[p * 16 + kl][nl + 0] = v.x;
    tile[p * 16 + kl][nl + 1] = v.y;
    tile[p * 16 + kl][nl + 2] = v.z;
    tile[p * 16 + kl][nl + 3] = v.w;
  }
  __syncthreads();
  for (int idx = t; idx < 4096; idx += 256) {
    int nl2 = idx >> 6, kl2 = idx & 63;
    O[(size_t)(n0 + nl2) * 1024 + k0 + kl2] = f2b(tile[kl2][nl2]);
  }
}

// ---------- K0c: dist_emb -> bf16 padded to 1024 rows ----------
__global__ __launch_bounds__(256) void k0c_conve(const float* __restrict__ E,
                                                 unsigned short* __restrict__ Eb) {
  int idx = blockIdx.x * 256 + threadIdx.x;   // < 65536
  int row = idx >> 6;
  float v = (row < 1023) ? E[idx] : 0.0f;
  Eb[idx] = f2b(v);
}

// ---------- K1: QKV GEMM  Xb[8192,1024] @ W -> Q/K bf16 [bh][s][dh], V -> Vt [bh][dh][s] ----------
__global__ __launch_bounds__(256) void k1_qkv(
    const unsigned short* __restrict__ Xb, const unsigned short* __restrict__ Wt,
    const float* __restrict__ bq, const float* __restrict__ bk,
    const float* __restrict__ bv, unsigned short* __restrict__ Qb,
    unsigned short* __restrict__ Kb, unsigned short* __restrict__ Vt) {
  __shared__ short As[128 * 72];
  __shared__ short Ws[128 * 72];
  int t = threadIdx.x;
  int wv = t >> 6, lane = t & 63, quad = lane >> 4, l15 = lane & 15;
  int wm = wv >> 1, wn = wv & 1;
  int m0 = blockIdx.x * 128, n0 = blockIdx.y * 128, z = blockIdx.z;
  const unsigned short* W = Wt + (size_t)z * 1024 * 1024;
  f32x4 acc[4][4];
#pragma unroll
  for (int i = 0; i < 4; ++i)
#pragma unroll
    for (int j = 0; j < 4; ++j) acc[i][j] = zero4();

  for (int kt = 0; kt < 16; ++kt) {
    int k0 = kt * 64;
    __syncthreads();
#pragma unroll
    for (int p = 0; p < 4; ++p) {
      int g = p * 256 + t;
      int row = g >> 3, cg = g & 7;
      int4 va = *(const int4*)(Xb + (size_t)(m0 + row) * 1024 + k0 + cg * 8);
      *(int4*)(&As[row * 72 + cg * 8]) = va;
      int4 vb = *(const int4*)(W + (size_t)(n0 + row) * 1024 + k0 + cg * 8);
      *(int4*)(&Ws[row * 72 + cg * 8]) = vb;
    }
    __syncthreads();
#pragma unroll
    for (int ks = 0; ks < 2; ++ks) {
      s16x8 a[4], bb[4];
#pragma unroll
      for (int i = 0; i < 4; ++i)
        a[i] = *(const s16x8*)(&As[(wm * 64 + i * 16 + l15) * 72 + ks * 32 + quad * 8]);
#pragma unroll
      for (int j = 0; j < 4; ++j)
        bb[j] = *(const s16x8*)(&Ws[(wn * 64 + j * 16 + l15) * 72 + ks * 32 + quad * 8]);
#pragma unroll
      for (int i = 0; i < 4; ++i)
#pragma unroll
        for (int j = 0; j < 4; ++j)
          acc[i][j] = mfma16(a[i], bb[j], acc[i][j]);
    }
  }
  const float* bias = (z == 0) ? bq : (z == 1) ? bk : bv;
#pragma unroll
  for (int i = 0; i < 4; ++i) {
    int mbase = m0 + wm * 64 + i * 16 + quad * 4;
#pragma unroll
    for (int j = 0; j < 4; ++j) {
      int n = n0 + wn * 64 + j * 16 + l15;
      float bvv = bias[n];
      int h = n >> 6, dh = n & 63;
#pragma unroll
      for (int r = 0; r < 4; ++r) {
        int m = mbase + r;
        int b = m >> 9, s = m & 511;
        unsigned short u = f2b(acc[i][j][r] + bvv);
        if (z == 2)
          Vt[(size_t)((b * 16 + h) * 64 + dh) * 512 + s] = u;
        else if (z == 0)
          Qb[(size_t)((b * 16 + h) * 512 + s) * 64 + dh] = u;
        else
          Kb[(size_t)((b * 16 + h) * 512 + s) * 64 + dh] = u;
      }
    }
  }
}

// ---------- K2 v2: fused attention, two-pass (online stats + recompute) ----------
// Per block: one (bh, 64-q-row tile). Wave wv owns q-rows [wv*16, wv*16+16).
// Pass A: per 64-key tile compute 16x64 score stripe in 4 f32x4 frags,
//         update per-lane online max/sum, discard scores.
// Pass B: recompute stripe, p = clip(exp(s-m)*c1/l + c0), bf16 -> wave-local
//         Ps, ctx += P@V (V B-frags direct from global).
__global__ __launch_bounds__(256, 3) void k2_attn(
    const unsigned short* __restrict__ Qb, const unsigned short* __restrict__ Kb,
    const unsigned short* __restrict__ Vt, const unsigned short* __restrict__ Eb,
    const float* __restrict__ gate, const float* __restrict__ mask,
    float* __restrict__ out) {
  __shared__ short Ks[64 * 72];     // K tile (rows=key, cols=dh)
  __shared__ short Ss1[128 * 68];   // Q@E^T col-major bf16 [dist 128][q 64+pad]
  __shared__ short Ss2[128 * 68];   // K@E^T col-major bf16 [dist 128][k 64+pad]
  __shared__ short Ps[64 * 72];     // P bf16, wave-local 16-row stripes

  int t = threadIdx.x;
  int wv = t >> 6, lane = t & 63, quad = lane >> 4, l15 = lane & 15;
  int bid = blockIdx.x;
  int bh = bid >> 3, qt = bid & 7;
  int b = bh >> 4, hh = bh & 15;
  int l0 = qt * 64;

  // staging indices for K tile (2 x int4 per thread)
  int srow = t >> 3, scg = t & 7;

  // Q A-frags for this wave's 16 q rows (constant all phases)
  s16x8 aq0, aq1;
  {
    const unsigned short* qp = Qb + ((size_t)bh * 512 + l0 + wv * 16 + l15) * 64 + quad * 8;
    aq0 = *(const s16x8*)(qp);
    aq1 = *(const s16x8*)(qp + 32);
  }

  float m[4], l[4];
#pragma unroll
  for (int r = 0; r < 4; ++r) { m[r] = -1e30f; l[r] = 0.0f; }

  // ================= Pass A: online softmax statistics =================
  for (int kt = 0; kt < 8; ++kt) {
    int r0 = kt * 64;
    // prefetch K tile into regs (no LDS dependency yet)
    int4 kv0 = *(const int4*)(Kb + ((size_t)bh * 512 + r0 + srow) * 64 + scg * 8);
    int4 kv1 = *(const int4*)(Kb + ((size_t)bh * 512 + r0 + srow + 32) * 64 + scg * 8);
    __syncthreads();   // prior tile's Ks/Ss readers done
    *(int4*)(&Ks[srow * 72 + scg * 8]) = kv0;
    *(int4*)(&Ks[(srow + 32) * 72 + scg * 8]) = kv1;
    __syncthreads();   // Ks visible
    s16x8 ak0 = *(const s16x8*)(&Ks[(wv * 16 + l15) * 72 + quad * 8]);
    s16x8 ak1 = *(const s16x8*)(&Ks[(wv * 16 + l15) * 72 + 32 + quad * 8]);
    int estart = (qt - kt) * 64 + 448;
    // S1 = Q@E^T, S2 = K@E^T -> LDS col-major bf16 (E B-frags direct global)
#pragma unroll
    for (int nf = 0; nf < 8; ++nf) {
      const s16x8* ep = (const s16x8*)(Eb + (size_t)(estart + nf * 16 + l15) * 64 + quad * 8);
      s16x8 eb0 = ep[0];
      s16x8 eb1 = ep[4];
      f32x4 s1 = mfma16(aq1, eb1, mfma16(aq0, eb0, zero4()));
      s16x4 w1;
      w1.x = (short)f2b(s1[0]); w1.y = (short)f2b(s1[1]);
      w1.z = (short)f2b(s1[2]); w1.w = (short)f2b(s1[3]);
      *(s16x4*)(&Ss1[(nf * 16 + l15) * 68 + wv * 16 + quad * 4]) = w1;
      f32x4 s2 = mfma16(ak1, eb1, mfma16(ak0, eb0, zero4()));
      s16x4 w2;
      w2.x = (short)f2b(s2[0]); w2.y = (short)f2b(s2[1]);
      w2.z = (short)f2b(s2[2]); w2.w = (short)f2b(s2[3]);
      *(s16x4*)(&Ss2[(nf * 16 + l15) * 68 + wv * 16 + quad * 4]) = w2;
    }
    // QK^T stripe
    f32x4 s[4];
#pragma unroll
    for (int nf = 0; nf < 4; ++nf) {
      s16x8 b0 = *(const s16x8*)(&Ks[(nf * 16 + l15) * 72 + quad * 8]);
      s16x8 b1 = *(const s16x8*)(&Ks[(nf * 16 + l15) * 72 + 32 + quad * 8]);
      s[nf] = mfma16(aq1, b1, mfma16(aq0, b0, zero4()));
    }
    __syncthreads();   // Ss visible
    float mk[4];
#pragma unroll
    for (int nf = 0; nf < 4; ++nf) {
      mk[nf] = mask[b * 512 + kt * 64 + nf * 16 + l15];
      int dr = nf * 16 + l15;
#pragma unroll
      for (int r = 0; r < 4; ++r) {
        int dl = wv * 16 + quad * 4 + r;
        int tt = dl - dr + 63;   // 0..126
        float p1 = b2f((unsigned short)Ss1[tt * 68 + dl]);
        float p2 = b2f((unsigned short)Ss2[tt * 68 + dr]);
        s[nf][r] += p1 + p2;
      }
    }
    // online max/sum update (per-lane columns only; cross-lane at end)
#pragma unroll
    for (int r = 0; r < 4; ++r) {
      float x0 = s[0][r] * 0.125f + mk[0];
      float x1 = s[1][r] * 0.125f + mk[1];
      float x2 = s[2][r] * 0.125f + mk[2];
      float x3 = s[3][r] * 0.125f + mk[3];
      float mt = fmaxf(fmaxf(x0, x1), fmaxf(x2, x3));
      float mn = fmaxf(m[r], mt);
      float sc = __expf(m[r] - mn);
      float ad = __expf(x0 - mn) + __expf(x1 - mn) + __expf(x2 - mn) + __expf(x3 - mn);
      l[r] = l[r] * sc + ad;
      m[r] = mn;
    }
  }

  // cross-lane (l15 group) combine of (m,l)
#pragma unroll
  for (int r = 0; r < 4; ++r) {
#pragma unroll
    for (int sft = 1; sft < 16; sft <<= 1) {
      float mo = __shfl_xor(m[r], sft);
      float lo = __shfl_xor(l[r], sft);
      float mn = fmaxf(m[r], mo);
      l[r] = l[r] * __expf(m[r] - mn) + lo * __expf(mo - mn);
      m[r] = mn;
    }
  }
  float f1[4];
#pragma unroll
  for (int r = 0; r < 4; ++r) f1[r] = 1.0234375f / l[r];
  const float c0 = -0.0234375f;

  // ================= Pass B: recompute + P@V =================
  f32x4 ctx[4];
#pragma unroll
  for (int nf = 0; nf < 4; ++nf) ctx[nf] = zero4();

  for (int kt = 0; kt < 8; ++kt) {
    int r0 = kt * 64;
    int4 kv0 = *(const int4*)(Kb + ((size_t)bh * 512 + r0 + srow) * 64 + scg * 8);
    int4 kv1 = *(const int4*)(Kb + ((size_t)bh * 512 + r0 + srow + 32) * 64 + scg * 8);
    __syncthreads();
    *(int4*)(&Ks[srow * 72 + scg * 8]) = kv0;
    *(int4*)(&Ks[(srow + 32) * 72 + scg * 8]) = kv1;
    __syncthreads();
    s16x8 ak0 = *(const s16x8*)(&Ks[(wv * 16 + l15) * 72 + quad * 8]);
    s16x8 ak1 = *(const s16x8*)(&Ks[(wv * 16 + l15) * 72 + 32 + quad * 8]);
    int estart = (qt - kt) * 64 + 448;
#pragma unroll
    for (int nf = 0; nf < 8; ++nf) {
      const s16x8* ep = (const s16x8*)(Eb + (size_t)(estart + nf * 16 + l15) * 64 + quad * 8);
      s16x8 eb0 = ep[0];
      s16x8 eb1 = ep[4];
      f32x4 s1 = mfma16(aq1, eb1, mfma16(aq0, eb0, zero4()));
      s16x4 w1;
      w1.x = (short)f2b(s1[0]); w1.y = (short)f2b(s1[1]);
      w1.z = (short)f2b(s1[2]); w1.w = (short)f2b(s1[3]);
      *(s16x4*)(&Ss1[(nf * 16 + l15) * 68 + wv * 16 + quad * 4]) = w1;
      f32x4 s2 = mfma16(ak1, eb1, mfma16(ak0, eb0, zero4()));
      s16x4 w2;
      w2.x = (short)f2b(s2[0]); w2.y = (short)f2b(s2[1]);
      w2.z = (short)f2b(s2[2]); w2.w = (short)f2b(s2[3]);
      *(s16x4*)(&Ss2[(nf * 16 + l15) * 68 + wv * 16 + quad * 4]) = w2;
    }
    f32x4 s[4];
#pragma unroll
    for (int nf = 0; nf < 4; ++nf) {
      s16x8 b0 = *(const s16x8*)(&Ks[(nf * 16 + l15) * 72 + quad * 8]);
      s16x8 b1 = *(const s16x8*)(&Ks[(nf * 16 + l15) * 72 + 32 + quad * 8]);
      s[nf] = mfma16(aq1, b1, mfma16(aq0, b0, zero4()));
    }
    __syncthreads();
#pragma unroll
    for (int nf = 0; nf < 4; ++nf) {
      float mkv = mask[b * 512 + kt * 64 + nf * 16 + l15];
      int dr = nf * 16 + l15;
#pragma unroll
      for (int r = 0; r < 4; ++r) {
        int dl = wv * 16 + quad * 4 + r;
        int tt = dl - dr + 63;
        float p1 = b2f((unsigned short)Ss1[tt * 68 + dl]);
        float p2 = b2f((unsigned short)Ss2[tt * 68 + dr]);
        float x = (s[nf][r] + p1 + p2) * 0.125f + mkv;
        float p = __expf(x - m[r]) * f1[r] + c0;
        p = fminf(fmaxf(p, 0.0f), 1.0f);
        Ps[(wv * 16 + quad * 4 + r) * 72 + nf * 16 + l15] = (short)f2b(p);
      }
    }
    // P@V for this tile (wave-local Ps; V B-frags direct from global)
    s16x8 ap0 = *(const s16x8*)(&Ps[(wv * 16 + l15) * 72 + quad * 8]);
    s16x8 ap1 = *(const s16x8*)(&Ps[(wv * 16 + l15) * 72 + 32 + quad * 8]);
#pragma unroll
    for (int nf = 0; nf < 4; ++nf) {
      const s16x8* vp = (const s16x8*)(Vt + ((size_t)bh * 64 + nf * 16 + l15) * 512 + kt * 64 + quad * 8);
      s16x8 vb0 = vp[0];
      s16x8 vb1 = vp[4];
      ctx[nf] = mfma16(ap1, vb1, mfma16(ap0, vb0, ctx[nf]));
    }
  }

  // ---- epilogue: * gate, write out [b][s][h*64+dh] fp32 ----
#pragma unroll
  for (int r = 0; r < 4; ++r) {
    int s = l0 + wv * 16 + quad * 4 + r;
    float g = gate[(size_t)bh * 512 + s];
#pragma unroll
    for (int nf = 0; nf < 4; ++nf)
      out[((size_t)(b * 512 + s)) * 1024 + hh * 64 + nf * 16 + l15] = ctx[nf][r] * g;
  }
}

// ---------- launch ----------
extern "C" void kernel_launch(void* const* d_in, const int* in_sizes, int n_in,
                              void* d_out, int out_size, void* d_ws, size_t ws_size,
                              hipStream_t stream) {
  const float* X = (const float*)d_in[0];
  const float* mask = (const float*)d_in[1];
  const float* Wq = (const float*)d_in[2];
  const float* bq = (const float*)d_in[3];
  const float* Wk = (const float*)d_in[4];
  const float* bk = (const float*)d_in[5];
  const float* Wv = (const float*)d_in[6];
  const float* bv = (const float*)d_in[7];
  const float* dist = (const float*)d_in[8];
  const float* gw = (const float*)d_in[9];
  const float* gb = (const float*)d_in[10];
  float* out = (float*)d_out;

  char* ws = (char*)d_ws;
  constexpr size_t OFF_XB = 0;                       // 8192*1024*2 = 16 MB
  constexpr size_t OFF_WT = 16777216;                // 3*1024*1024*2 = 6 MB
  constexpr size_t OFF_QB = OFF_WT + 6291456;        // 16 MB
  constexpr size_t OFF_KB = OFF_QB + 16777216;       // 16 MB
  constexpr size_t OFF_VT = OFF_KB + 16777216;       // 16 MB
  constexpr size_t OFF_EB = OFF_VT + 16777216;       // 1024*64*2
  constexpr size_t OFF_GA = OFF_EB + 131072;         // 256*512*4

  unsigned short* Xb = (unsigned short*)(ws + OFF_XB);
  unsigned short* Wt = (unsigned short*)(ws + OFF_WT);
  unsigned short* Qb = (unsigned short*)(ws + OFF_QB);
  unsigned short* Kb = (unsigned short*)(ws + OFF_KB);
  unsigned short* Vt = (unsigned short*)(ws + OFF_VT);
  unsigned short* Eb = (unsigned short*)(ws + OFF_EB);
  float* gate = (float*)(ws + OFF_GA);

  hipLaunchKernelGGL(k0a_convx_gate, dim3(8192), dim3(256), 0, stream, X, gw, gb, Xb, gate);
  hipLaunchKernelGGL(k0b_wtrans, dim3(16, 16, 3), dim3(256), 0, stream, Wq, Wk, Wv, Wt);
  hipLaunchKernelGGL(k0c_conve, dim3(256), dim3(256), 0, stream, dist, Eb);
  hipLaunchKernelGGL(k1_qkv, dim3(64, 8, 3), dim3(256), 0, stream,
                     Xb, Wt, bq, bk, bv, Qb, Kb, Vt);
  hipLaunchKernelGGL(k2_attn, dim3(2048), dim3(256), 0, stream,
                     Qb, Kb, Vt, Eb, gate, mask, out);
}

// Round 4
// 405.908 us; speedup vs baseline: 1.8874x; 1.3494x over previous
//
#include <hip/hip_runtime.h>

// ---------- types / helpers ----------
typedef __attribute__((ext_vector_type(8))) short s16x8;
typedef __attribute__((ext_vector_type(4))) short s16x4;
typedef __attribute__((ext_vector_type(4))) float f32x4;

__device__ __forceinline__ f32x4 mfma16(s16x8 a, s16x8 b, f32x4 c) {
  return __builtin_amdgcn_mfma_f32_16x16x32_bf16(a, b, c, 0, 0, 0);
}
__device__ __forceinline__ f32x4 zero4() {
  f32x4 z = {0.f, 0.f, 0.f, 0.f};
  return z;
}

__device__ __forceinline__ unsigned short f2b(float f) {
  unsigned u = __float_as_uint(f);
  u = u + 0x7fffu + ((u >> 16) & 1u);          // RNE
  return (unsigned short)(u >> 16);
}
__device__ __forceinline__ float b2f(unsigned short u) {
  return __uint_as_float(((unsigned)u) << 16);
}
// pack two f32 -> two bf16 (RNE) in one uint
__device__ __forceinline__ unsigned packbf(float a, float b) {
  return (unsigned)f2b(a) | ((unsigned)f2b(b) << 16);
}

// problem constants
// B=16 S=512 H=16 DH=64 D=1024, BH=256

// ---------- K0a: X fp32 -> bf16, + per-head gate ----------
__global__ __launch_bounds__(256) void k0a_convx_gate(
    const float* __restrict__ X, const float* __restrict__ gw,
    const float* __restrict__ gb, unsigned short* __restrict__ Xb,
    float* __restrict__ gate) {
  int row = blockIdx.x;              // b*512 + s, 0..8191
  int t = threadIdx.x;               // 256
  const float* xr = X + (size_t)row * 1024;
  float4 x = *(const float4*)(xr + t * 4);
  s16x4 o;
  o.x = (short)f2b(x.x); o.y = (short)f2b(x.y);
  o.z = (short)f2b(x.z); o.w = (short)f2b(x.w);
  *(s16x4*)(&Xb[(size_t)row * 1024 + t * 4]) = o;
  // gate: head h = t>>4, 16 threads per head, 4 elems each
  int h = t >> 4;
  int e0 = (t & 15) * 4;
  const float* g4 = gw + h * 64 + e0;
  float part = x.x * g4[0] + x.y * g4[1] + x.z * g4[2] + x.w * g4[3];
  part += __shfl_xor(part, 1);
  part += __shfl_xor(part, 2);
  part += __shfl_xor(part, 4);
  part += __shfl_xor(part, 8);
  if ((t & 15) == 0) {
    int b = row >> 9, s = row & 511;
    float z = part + gb[h];
    gate[((size_t)(b * 16 + h)) * 512 + s] = 1.0f / (1.0f + __expf(-z));
  }
}

// ---------- K0b: W [k][n] fp32 -> Wt [n][k] bf16 (x3) ----------
__global__ __launch_bounds__(256) void k0b_wtrans(
    const float* __restrict__ Wq, const float* __restrict__ Wk,
    const float* __restrict__ Wv, unsigned short* __restrict__ Wt) {
  __shared__ float tile[64][68];
  int z = blockIdx.z;
  const float* W = (z == 0) ? Wq : (z == 1) ? Wk : Wv;
  unsigned short* O = Wt + (size_t)z * 1024 * 1024;
  int k0 = blockIdx.x * 64, n0 = blockIdx.y * 64;
  int t = threadIdx.x;
  int kl = t >> 4, nl = (t & 15) * 4;
#pragma unroll
  for (int p = 0; p < 4; ++p) {
    float4 v = *(const float4*)(W + (size_t)(k0 + p * 16 + kl) * 1024 + n0 + nl);
    tile[p * 16 + kl][nl + 0] = v.x;
    tile[p * 16 + kl][nl + 1] = v.y;
    tile[p * 16 + kl][nl + 2] = v.z;
    tile[p * 16 + kl][nl + 3] = v.w;
  }
  __syncthreads();
  for (int idx = t; idx < 4096; idx += 256) {
    int nl2 = idx >> 6, kl2 = idx & 63;
    O[(size_t)(n0 + nl2) * 1024 + k0 + kl2] = f2b(tile[kl2][nl2]);
  }
}

// ---------- K0c: dist_emb -> bf16 padded to 1024 rows ----------
__global__ __launch_bounds__(256) void k0c_conve(const float* __restrict__ E,
                                                 unsigned short* __restrict__ Eb) {
  int idx = blockIdx.x * 256 + threadIdx.x;   // < 65536
  int row = idx >> 6;
  float v = (row < 1023) ? E[idx] : 0.0f;
  Eb[idx] = f2b(v);
}

// ---------- K1: QKV GEMM  Xb[8192,1024] @ W -> Q/K bf16 [bh][s][dh], V -> Vt [bh][dh][s] ----------
__global__ __launch_bounds__(256) void k1_qkv(
    const unsigned short* __restrict__ Xb, const unsigned short* __restrict__ Wt,
    const float* __restrict__ bq, const float* __restrict__ bk,
    const float* __restrict__ bv, unsigned short* __restrict__ Qb,
    unsigned short* __restrict__ Kb, unsigned short* __restrict__ Vt) {
  __shared__ short As[128 * 72];
  __shared__ short Ws[128 * 72];
  int t = threadIdx.x;
  int wv = t >> 6, lane = t & 63, quad = lane >> 4, l15 = lane & 15;
  int wm = wv >> 1, wn = wv & 1;
  int m0 = blockIdx.x * 128, n0 = blockIdx.y * 128, z = blockIdx.z;
  const unsigned short* W = Wt + (size_t)z * 1024 * 1024;
  f32x4 acc[4][4];
#pragma unroll
  for (int i = 0; i < 4; ++i)
#pragma unroll
    for (int j = 0; j < 4; ++j) acc[i][j] = zero4();

  for (int kt = 0; kt < 16; ++kt) {
    int k0 = kt * 64;
    __syncthreads();
#pragma unroll
    for (int p = 0; p < 4; ++p) {
      int g = p * 256 + t;
      int row = g >> 3, cg = g & 7;
      int4 va = *(const int4*)(Xb + (size_t)(m0 + row) * 1024 + k0 + cg * 8);
      *(int4*)(&As[row * 72 + cg * 8]) = va;
      int4 vb = *(const int4*)(W + (size_t)(n0 + row) * 1024 + k0 + cg * 8);
      *(int4*)(&Ws[row * 72 + cg * 8]) = vb;
    }
    __syncthreads();
#pragma unroll
    for (int ks = 0; ks < 2; ++ks) {
      s16x8 a[4], bb[4];
#pragma unroll
      for (int i = 0; i < 4; ++i)
        a[i] = *(const s16x8*)(&As[(wm * 64 + i * 16 + l15) * 72 + ks * 32 + quad * 8]);
#pragma unroll
      for (int j = 0; j < 4; ++j)
        bb[j] = *(const s16x8*)(&Ws[(wn * 64 + j * 16 + l15) * 72 + ks * 32 + quad * 8]);
#pragma unroll
      for (int i = 0; i < 4; ++i)
#pragma unroll
        for (int j = 0; j < 4; ++j)
          acc[i][j] = mfma16(a[i], bb[j], acc[i][j]);
    }
  }
  const float* bias = (z == 0) ? bq : (z == 1) ? bk : bv;
#pragma unroll
  for (int i = 0; i < 4; ++i) {
    int mbase = m0 + wm * 64 + i * 16 + quad * 4;
#pragma unroll
    for (int j = 0; j < 4; ++j) {
      int n = n0 + wn * 64 + j * 16 + l15;
      float bvv = bias[n];
      int h = n >> 6, dh = n & 63;
#pragma unroll
      for (int r = 0; r < 4; ++r) {
        int m = mbase + r;
        int b = m >> 9, s = m & 511;
        unsigned short u = f2b(acc[i][j][r] + bvv);
        if (z == 2)
          Vt[(size_t)((b * 16 + h) * 64 + dh) * 512 + s] = u;
        else if (z == 0)
          Qb[(size_t)((b * 16 + h) * 512 + s) * 64 + dh] = u;
        else
          Kb[(size_t)((b * 16 + h) * 512 + s) * 64 + dh] = u;
      }
    }
  }
}

// ---------- K2 v3: fused attention, SINGLE pass with packed-bf16 exp stash ----------
// Per block: one (bh, 64-q-row tile). Wave wv owns q-rows [wv*16, wv*16+16).
// For each 64-key tile: scores via MFMA (QK^T + diag-gathered Q@E^T, K@E^T),
// ex = exp(x) WITHOUT max subtraction (|x| small; f32 exp safe), accumulate
// row-sum l, stash ex as packed bf16 (64 VGPRs, statically indexed — the kt
// loop MUST stay fully unrolled or the stash spills to scratch).
// Epilogue: reduce l, p = clip(ex*c1/l + c0), Ps (wave-local) -> P@V.
__global__ __launch_bounds__(256, 3) void k2_attn(
    const unsigned short* __restrict__ Qb, const unsigned short* __restrict__ Kb,
    const unsigned short* __restrict__ Vt, const unsigned short* __restrict__ Eb,
    const float* __restrict__ gate, const float* __restrict__ mask,
    float* __restrict__ out) {
  __shared__ short Ks[64 * 72];     // K tile (rows=key, cols=dh)
  __shared__ short Ss1[128 * 68];   // Q@E^T col-major bf16 [dist 128][q 64+pad]
  __shared__ short Ss2[128 * 68];   // K@E^T col-major bf16 [dist 128][k 64+pad]
  __shared__ short Ps[64 * 72];     // P bf16, wave-local 16-row stripes

  int t = threadIdx.x;
  int wv = t >> 6, lane = t & 63, quad = lane >> 4, l15 = lane & 15;
  int bid = blockIdx.x;
  int bh = bid >> 3, qt = bid & 7;
  int b = bh >> 4, hh = bh & 15;
  int l0 = qt * 64;

  // staging indices for K tile (2 x int4 per thread)
  int srow = t >> 3, scg = t & 7;

  // Q A-frags for this wave's 16 q rows (constant all phases)
  s16x8 aq0, aq1;
  {
    const unsigned short* qp = Qb + ((size_t)bh * 512 + l0 + wv * 16 + l15) * 64 + quad * 8;
    aq0 = *(const s16x8*)(qp);
    aq1 = *(const s16x8*)(qp + 32);
  }

  float lsum[4];
#pragma unroll
  for (int r = 0; r < 4; ++r) lsum[r] = 0.0f;
  unsigned stash[64];   // [kt][nf][pair]: ex(r=0,1) and ex(r=2,3) packed bf16

  // ================= single pass: scores -> exp -> stash =================
#pragma unroll
  for (int kt = 0; kt < 8; ++kt) {
    int r0 = kt * 64;
    // prefetch K tile into regs (no LDS dependency yet)
    int4 kv0 = *(const int4*)(Kb + ((size_t)bh * 512 + r0 + srow) * 64 + scg * 8);
    int4 kv1 = *(const int4*)(Kb + ((size_t)bh * 512 + r0 + srow + 32) * 64 + scg * 8);
    __syncthreads();   // prior tile's Ks/Ss readers done
    *(int4*)(&Ks[srow * 72 + scg * 8]) = kv0;
    *(int4*)(&Ks[(srow + 32) * 72 + scg * 8]) = kv1;
    __syncthreads();   // Ks visible
    s16x8 ak0 = *(const s16x8*)(&Ks[(wv * 16 + l15) * 72 + quad * 8]);
    s16x8 ak1 = *(const s16x8*)(&Ks[(wv * 16 + l15) * 72 + 32 + quad * 8]);
    int estart = (qt - kt) * 64 + 448;
    // S1 = Q@E^T, S2 = K@E^T -> LDS col-major bf16 (E B-frags direct global)
#pragma unroll
    for (int nf = 0; nf < 8; ++nf) {
      const s16x8* ep = (const s16x8*)(Eb + (size_t)(estart + nf * 16 + l15) * 64 + quad * 8);
      s16x8 eb0 = ep[0];
      s16x8 eb1 = ep[4];
      f32x4 s1 = mfma16(aq1, eb1, mfma16(aq0, eb0, zero4()));
      s16x4 w1;
      w1.x = (short)f2b(s1[0]); w1.y = (short)f2b(s1[1]);
      w1.z = (short)f2b(s1[2]); w1.w = (short)f2b(s1[3]);
      *(s16x4*)(&Ss1[(nf * 16 + l15) * 68 + wv * 16 + quad * 4]) = w1;
      f32x4 s2 = mfma16(ak1, eb1, mfma16(ak0, eb0, zero4()));
      s16x4 w2;
      w2.x = (short)f2b(s2[0]); w2.y = (short)f2b(s2[1]);
      w2.z = (short)f2b(s2[2]); w2.w = (short)f2b(s2[3]);
      *(s16x4*)(&Ss2[(nf * 16 + l15) * 68 + wv * 16 + quad * 4]) = w2;
    }
    // QK^T stripe
    f32x4 s[4];
#pragma unroll
    for (int nf = 0; nf < 4; ++nf) {
      s16x8 b0 = *(const s16x8*)(&Ks[(nf * 16 + l15) * 72 + quad * 8]);
      s16x8 b1 = *(const s16x8*)(&Ks[(nf * 16 + l15) * 72 + 32 + quad * 8]);
      s[nf] = mfma16(aq1, b1, mfma16(aq0, b0, zero4()));
    }
    __syncthreads();   // Ss visible
#pragma unroll
    for (int nf = 0; nf < 4; ++nf) {
      float mkv = mask[b * 512 + kt * 64 + nf * 16 + l15];
      int dr = nf * 16 + l15;
      float ex[4];
#pragma unroll
      for (int r = 0; r < 4; ++r) {
        int dl = wv * 16 + quad * 4 + r;
        int tt = dl - dr + 63;   // 0..126
        float p1 = b2f((unsigned short)Ss1[tt * 68 + dl]);
        float p2 = b2f((unsigned short)Ss2[tt * 68 + dr]);
        float x = (s[nf][r] + p1 + p2) * 0.125f + mkv;
        ex[r] = __expf(x);
        lsum[r] += ex[r];
      }
      stash[kt * 8 + nf * 2 + 0] = packbf(ex[0], ex[1]);
      stash[kt * 8 + nf * 2 + 1] = packbf(ex[2], ex[3]);
    }
  }

  // cross-lane (l15 group) combine of row sums
#pragma unroll
  for (int r = 0; r < 4; ++r) {
    lsum[r] += __shfl_xor(lsum[r], 1);
    lsum[r] += __shfl_xor(lsum[r], 2);
    lsum[r] += __shfl_xor(lsum[r], 4);
    lsum[r] += __shfl_xor(lsum[r], 8);
  }
  float f1[4];
#pragma unroll
  for (int r = 0; r < 4; ++r) f1[r] = 1.0234375f / lsum[r];
  const float c0 = -0.0234375f;

  // ================= epilogue: p = clip(ex*f1 + c0) -> Ps -> P@V =================
  f32x4 ctx[4];
#pragma unroll
  for (int nf = 0; nf < 4; ++nf) ctx[nf] = zero4();

#pragma unroll
  for (int kt = 0; kt < 8; ++kt) {
#pragma unroll
    for (int nf = 0; nf < 4; ++nf) {
      unsigned u0 = stash[kt * 8 + nf * 2 + 0];
      unsigned u1 = stash[kt * 8 + nf * 2 + 1];
      float e0 = b2f((unsigned short)(u0 & 0xffff));
      float e1 = b2f((unsigned short)(u0 >> 16));
      float e2 = b2f((unsigned short)(u1 & 0xffff));
      float e3 = b2f((unsigned short)(u1 >> 16));
      float p0 = fminf(fmaxf(e0 * f1[0] + c0, 0.0f), 1.0f);
      float p1 = fminf(fmaxf(e1 * f1[1] + c0, 0.0f), 1.0f);
      float p2 = fminf(fmaxf(e2 * f1[2] + c0, 0.0f), 1.0f);
      float p3 = fminf(fmaxf(e3 * f1[3] + c0, 0.0f), 1.0f);
      int rowb = wv * 16 + quad * 4;
      Ps[(rowb + 0) * 72 + nf * 16 + l15] = (short)f2b(p0);
      Ps[(rowb + 1) * 72 + nf * 16 + l15] = (short)f2b(p1);
      Ps[(rowb + 2) * 72 + nf * 16 + l15] = (short)f2b(p2);
      Ps[(rowb + 3) * 72 + nf * 16 + l15] = (short)f2b(p3);
    }
    // P@V for this tile (wave-local Ps; V B-frags direct from global)
    s16x8 ap0 = *(const s16x8*)(&Ps[(wv * 16 + l15) * 72 + quad * 8]);
    s16x8 ap1 = *(const s16x8*)(&Ps[(wv * 16 + l15) * 72 + 32 + quad * 8]);
#pragma unroll
    for (int nf = 0; nf < 4; ++nf) {
      const s16x8* vp = (const s16x8*)(Vt + ((size_t)bh * 64 + nf * 16 + l15) * 512 + kt * 64 + quad * 8);
      s16x8 vb0 = vp[0];
      s16x8 vb1 = vp[4];
      ctx[nf] = mfma16(ap1, vb1, mfma16(ap0, vb0, ctx[nf]));
    }
  }

  // ---- epilogue: * gate, write out [b][s][h*64+dh] fp32 ----
#pragma unroll
  for (int r = 0; r < 4; ++r) {
    int s = l0 + wv * 16 + quad * 4 + r;
    float g = gate[(size_t)bh * 512 + s];
#pragma unroll
    for (int nf = 0; nf < 4; ++nf)
      out[((size_t)(b * 512 + s)) * 1024 + hh * 64 + nf * 16 + l15] = ctx[nf][r] * g;
  }
}

// ---------- launch ----------
extern "C" void kernel_launch(void* const* d_in, const int* in_sizes, int n_in,
                              void* d_out, int out_size, void* d_ws, size_t ws_size,
                              hipStream_t stream) {
  const float* X = (const float*)d_in[0];
  const float* mask = (const float*)d_in[1];
  const float* Wq = (const float*)d_in[2];
  const float* bq = (const float*)d_in[3];
  const float* Wk = (const float*)d_in[4];
  const float* bk = (const float*)d_in[5];
  const float* Wv = (const float*)d_in[6];
  const float* bv = (const float*)d_in[7];
  const float* dist = (const float*)d_in[8];
  const float* gw = (const float*)d_in[9];
  const float* gb = (const float*)d_in[10];
  float* out = (float*)d_out;

  char* ws = (char*)d_ws;
  constexpr size_t OFF_XB = 0;                       // 8192*1024*2 = 16 MB
  constexpr size_t OFF_WT = 16777216;                // 3*1024*1024*2 = 6 MB
  constexpr size_t OFF_QB = OFF_WT + 6291456;        // 16 MB
  constexpr size_t OFF_KB = OFF_QB + 16777216;       // 16 MB
  constexpr size_t OFF_VT = OFF_KB + 16777216;       // 16 MB
  constexpr size_t OFF_EB = OFF_VT + 16777216;       // 1024*64*2
  constexpr size_t OFF_GA = OFF_EB + 131072;         // 256*512*4

  unsigned short* Xb = (unsigned short*)(ws + OFF_XB);
  unsigned short* Wt = (unsigned short*)(ws + OFF_WT);
  unsigned short* Qb = (unsigned short*)(ws + OFF_QB);
  unsigned short* Kb = (unsigned short*)(ws + OFF_KB);
  unsigned short* Vt = (unsigned short*)(ws + OFF_VT);
  unsigned short* Eb = (unsigned short*)(ws + OFF_EB);
  float* gate = (float*)(ws + OFF_GA);

  hipLaunchKernelGGL(k0a_convx_gate, dim3(8192), dim3(256), 0, stream, X, gw, gb, Xb, gate);
  hipLaunchKernelGGL(k0b_wtrans, dim3(16, 16, 3), dim3(256), 0, stream, Wq, Wk, Wv, Wt);
  hipLaunchKernelGGL(k0c_conve, dim3(256), dim3(256), 0, stream, dist, Eb);
  hipLaunchKernelGGL(k1_qkv, dim3(64, 8, 3), dim3(256), 0, stream,
                     Xb, Wt, bq, bk, bv, Qb, Kb, Vt);
  hipLaunchKernelGGL(k2_attn, dim3(2048), dim3(256), 0, stream,
                     Qb, Kb, Vt, Eb, gate, mask, out);
}